// Round 14
// baseline (194.674 us; speedup 1.0000x reference)
//
#include <hip/hip_runtime.h>
#include <hip/hip_fp16.h>
#include <math.h>

#define IN_F 64
#define OUT_F 32
#define NEG_SLOPE 0.2f

#define BK_SHIFT 7
#define BK 128           // nodes per bucket
#define NBMAX 1024       // max buckets (N <= 131072)
#define NBLKA 256        // edge-pass block count
#define PSTAGE 10        // k_place register staging (mean count ~2046 < 2560)
#define SB 64            // buckets per scan block (64 KB LDS transpose tile)

typedef _Float16 half8_t __attribute__((ext_vector_type(8)));
typedef float float4_t __attribute__((ext_vector_type(4)));

__device__ __forceinline__ float leaky(float v) {
    return (v > 0.0f) ? v : NEG_SLOPE * v;
}

// Inclusive block scan, 256 threads. wsum: >=4-int LDS scratch.
__device__ __forceinline__ int incScan256(int v, int tid, int* wsum) {
    const int lane = tid & 63, wid = tid >> 6;
    #pragma unroll
    for (int m = 1; m < 64; m <<= 1) {
        int u = __shfl_up(v, m);
        if (lane >= m) v += u;
    }
    if (lane == 63) wsum[wid] = v;
    __syncthreads();
    int add = 0;
    for (int k = 0; k < wid; ++k) add += wsum[k];
    __syncthreads();
    return v + add;
}

// Inclusive block scan, 512 threads. wsum: >=8-int LDS scratch.
__device__ __forceinline__ int incScan512(int v, int tid, int* wsum) {
    const int lane = tid & 63, wid = tid >> 6;
    #pragma unroll
    for (int m = 1; m < 64; m <<= 1) {
        int u = __shfl_up(v, m);
        if (lane >= m) v += u;
    }
    if (lane == 63) wsum[wid] = v;
    __syncthreads();
    int add = 0;
    for (int k = 0; k < wid; ++k) add += wsum[k];
    __syncthreads();
    return v + add;
}

// Fused: blocks [0, PB) MFMA projection (16 nodes/wave, 64/block, no LDS);
// blocks [PB, PB+NBLKA) coarse histogram. hist layout: [blk][b] (row-major,
// stride NB) -> coalesced writes here, coalesced reads in k_bpart.
__global__ __launch_bounds__(256) void k_projhist(
        const float* __restrict__ x, const float* __restrict__ W,
        const float* __restrict__ att_src, const float* __restrict__ att_dst,
        __half2* __restrict__ h2, float* __restrict__ asrc, float* __restrict__ adst,
        const int* __restrict__ dst, int* __restrict__ hist,
        int N, int NB, int E, int epb, int PB) {
    __shared__ int smem[2560];               // 10 KB (hist role only)
    const int tid = threadIdx.x;

    if (blockIdx.x >= PB) {
        // ---- coarse histogram role: hist[blk*NB + b] (coalesced row) ----
        int* lh = smem;
        const int blk = blockIdx.x - PB;
        for (int i = tid; i < NB; i += 256) lh[i] = 0;
        __syncthreads();
        const int e0 = blk * epb, e1 = min(E, e0 + epb);
        for (int e = e0 + tid; e < e1; e += 256) atomicAdd(&lh[dst[e] >> BK_SHIFT], 1);
        __syncthreads();
        for (int b = tid; b < NB; b += 256) hist[(size_t)blk * NB + b] = lh[b];
        return;
    }

    // ---- MFMA projection role (layouts HW-verified: §3 / m89) ----
    const int wv   = tid >> 6;               // wave 0..3
    const int lane = tid & 63;
    const int m    = lane & 15;
    const int quad = lane >> 4;
    const int node0 = (blockIdx.x * 4 + wv) * 16;
    if (node0 >= N) return;

    const int kb = quad * 8;
    half8_t b00, b01, b10, b11;
    #pragma unroll
    for (int j = 0; j < 8; ++j) {
        b00[j] = (_Float16)W[(kb + j) * OUT_F + m];
        b01[j] = (_Float16)W[(32 + kb + j) * OUT_F + m];
        b10[j] = (_Float16)W[(kb + j) * OUT_F + 16 + m];
        b11[j] = (_Float16)W[(32 + kb + j) * OUT_F + 16 + m];
    }
    const int row = min(node0 + m, N - 1);
    const float* xr = x + (size_t)row * IN_F + kb;
    float4_t xa = *(const float4_t*)(xr);
    float4_t xb = *(const float4_t*)(xr + 4);
    float4_t xc = *(const float4_t*)(xr + 32);
    float4_t xd = *(const float4_t*)(xr + 36);
    half8_t a0, a1;
    #pragma unroll
    for (int j = 0; j < 4; ++j) {
        a0[j] = (_Float16)xa[j]; a0[4 + j] = (_Float16)xb[j];
        a1[j] = (_Float16)xc[j]; a1[4 + j] = (_Float16)xd[j];
    }
    float4_t acc0 = {0.f, 0.f, 0.f, 0.f};
    float4_t acc1 = {0.f, 0.f, 0.f, 0.f};
    acc0 = __builtin_amdgcn_mfma_f32_16x16x32_f16(a0, b00, acc0, 0, 0, 0);
    acc0 = __builtin_amdgcn_mfma_f32_16x16x32_f16(a1, b01, acc0, 0, 0, 0);
    acc1 = __builtin_amdgcn_mfma_f32_16x16x32_f16(a0, b10, acc1, 0, 0, 0);
    acc1 = __builtin_amdgcn_mfma_f32_16x16x32_f16(a1, b11, acc1, 0, 0, 0);

    const float aS0 = att_src[m], aS1 = att_src[16 + m];
    const float aD0 = att_dst[m], aD1 = att_dst[16 + m];
    #pragma unroll
    for (int r = 0; r < 4; ++r) {
        const int node = node0 + quad * 4 + r;
        float h0 = acc0[r], h1 = acc1[r];
        float h0p = __shfl_xor(h0, 1);
        float h1p = __shfl_xor(h1, 1);
        if (node < N && (m & 1) == 0) {
            __half2 hv;
            hv.x = __float2half_rn(h0); hv.y = __float2half_rn(h0p);
            h2[(size_t)node * 16 + (m >> 1)] = hv;
            __half2 hw;
            hw.x = __float2half_rn(h1); hw.y = __float2half_rn(h1p);
            h2[(size_t)node * 16 + 8 + (m >> 1)] = hw;
        }
        float vs = h0 * aS0 + h1 * aS1;
        float vd = h0 * aD0 + h1 * aD1;
        #pragma unroll
        for (int mm = 1; mm < 16; mm <<= 1) {
            vs += __shfl_xor(vs, mm);
            vd += __shfl_xor(vd, mm);
        }
        if (node < N && m == 0) {
            asrc[node] = vs;
            adst[node] = vd;
        }
    }
}

// Scan 1 (transposed layout): 64 buckets per block. LDS tile [256][64],
// coalesced row loads, serial per-thread scan over the 256 block entries
// (2 lanes/bank = free), coalesced store back + bucket totals.
__global__ __launch_bounds__(256) void k_scan1(int* __restrict__ hist,
                                               int* __restrict__ bsum, int NB) {
    __shared__ int lbuf[NBLKA * SB];        // 64 KB
    const int bb0 = blockIdx.x * SB;
    const int tid = threadIdx.x;
    for (int i = tid; i < NBLKA * SB; i += 256) {
        int blk = i >> 6;                    // /SB
        int bo  = i & (SB - 1);
        int b = bb0 + bo;
        lbuf[blk * SB + bo] = (b < NB) ? hist[(size_t)blk * NB + b] : 0;
    }
    __syncthreads();
    if (tid < SB) {
        int run = 0;
        #pragma unroll 8
        for (int blk = 0; blk < NBLKA; ++blk) {
            int v = lbuf[blk * SB + tid];
            lbuf[blk * SB + tid] = run;
            run += v;
        }
        int b = bb0 + tid;
        if (b < NB) bsum[b] = run;
    }
    __syncthreads();
    for (int i = tid; i < NBLKA * SB; i += 256) {
        int blk = i >> 6;
        int bo  = i & (SB - 1);
        int b = bb0 + bo;
        if (b < NB) hist[(size_t)blk * NB + b] = lbuf[blk * SB + bo];
    }
}

// Pass B: 512 threads/block. Locally scan bucket totals -> bbase (LDS), seed
// per-bucket cursors from the (coalesced) hist row, place packed records.
__global__ __launch_bounds__(512) void k_bpart(const int* __restrict__ src,
                                               const int* __restrict__ dst,
                                               const int* __restrict__ hist,
                                               const int* __restrict__ bsum,
                                               int* __restrict__ recs,
                                               int NB, int E, int epb) {
    __shared__ int tt[NBMAX];
    __shared__ int lcur[NBMAX];
    __shared__ int wsum[8];
    const int tid = threadIdx.x, blk = blockIdx.x;
    for (int i = tid; i < NBMAX; i += 512) tt[i] = (i < NB) ? bsum[i] : 0;
    __syncthreads();
    {
        int a0 = tt[tid * 2], a1 = tt[tid * 2 + 1];
        int s = a0 + a1;
        int inc = incScan512(s, tid, wsum);
        int run = inc - s;
        tt[tid * 2] = run; run += a0;
        tt[tid * 2 + 1] = run;
    }
    __syncthreads();
    for (int b = tid; b < NB; b += 512)
        lcur[b] = hist[(size_t)blk * NB + b] + tt[b];   // coalesced row read
    __syncthreads();
    const int e0 = blk * epb, e1 = min(E, e0 + epb);
    for (int e = e0 + tid; e < e1; e += 512) {
        int s = src[e];
        int d = dst[e];
        int p = atomicAdd(&lcur[d >> BK_SHIFT], 1);     // LDS cursor, block-private
        recs[p] = ((d & (BK - 1)) << 17) | s;
    }
}

// Pass C: one block per bucket (128 nodes). Local bbase scan for cb0/cb1,
// register-staged records, fine histogram + scan, emit cnt/offs, place col.
__global__ __launch_bounds__(256) void k_place(const int* __restrict__ recs,
                                               const int* __restrict__ bsum,
                                               int* __restrict__ cnt,
                                               int* __restrict__ offs,
                                               int* __restrict__ col,
                                               int NB, int E, int N) {
    __shared__ int tt[NBMAX];
    __shared__ int fineCnt[BK];
    __shared__ int cur[BK];
    __shared__ int wsum[4];
    const int b = blockIdx.x, tid = threadIdx.x;
    for (int i = tid; i < NBMAX; i += 256) tt[i] = (i < NB) ? bsum[i] : 0;
    __syncthreads();
    {
        int a0 = tt[tid * 4], a1 = tt[tid * 4 + 1], a2 = tt[tid * 4 + 2], a3 = tt[tid * 4 + 3];
        int s = a0 + a1 + a2 + a3;
        int inc = incScan256(s, tid, wsum);
        int run = inc - s;
        tt[tid * 4] = run;     run += a0;
        tt[tid * 4 + 1] = run; run += a1;
        tt[tid * 4 + 2] = run; run += a2;
        tt[tid * 4 + 3] = run;
    }
    __syncthreads();
    const int cb0 = tt[b];
    const int cb1 = (b + 1 < NB) ? tt[b + 1] : E;
    const int count = cb1 - cb0;
    int myrec[PSTAGE];
    if (tid < BK) fineCnt[tid] = 0;
    __syncthreads();
    #pragma unroll
    for (int k = 0; k < PSTAGE; ++k) {
        int i = tid + k * 256;
        if (i < count) {
            int v = recs[cb0 + i];
            myrec[k] = v;
            atomicAdd(&fineCnt[v >> 17], 1);
        }
    }
    for (int i = tid + PSTAGE * 256; i < count; i += 256)   // statistically never
        atomicAdd(&fineCnt[recs[cb0 + i] >> 17], 1);
    __syncthreads();
    const int v0 = (tid < BK) ? fineCnt[tid] : 0;
    const int inc = incScan256(v0, tid, wsum);
    const int excl = inc - v0;
    if (tid < BK) {
        const int node = (b << BK_SHIFT) + tid;
        if (node < N) {
            cnt[node]  = v0;
            offs[node] = cb0 + excl;
        }
        cur[tid] = cb0 + excl;
    }
    __syncthreads();
    #pragma unroll
    for (int k = 0; k < PSTAGE; ++k) {
        int i = tid + k * 256;
        if (i < count) {
            int r = myrec[k];
            int p = atomicAdd(&cur[r >> 17], 1);
            col[p] = r & 0x1FFFF;
        }
    }
    for (int i = tid + PSTAGE * 256; i < count; i += 256) {
        int r = recs[cb0 + i];
        int p = atomicAdd(&cur[r >> 17], 1);
        col[p] = r & 0x1FFFF;
    }
}

// Gather: one wave per node, 4 groups x 16 lanes. Within each 4-lane cluster,
// lane eo computes only slot eo's col/asrc/exp; s and p shared via shfl_xor
// (1/2/3). Cuts redundant exp + scalar-load issue ~4x. Predicated, no tail.
__global__ void k_gather(const int* __restrict__ col, const int* __restrict__ offs,
                         const int* __restrict__ cnt, const float* __restrict__ asrc,
                         const float* __restrict__ adst, const __half2* __restrict__ h2,
                         const float* __restrict__ bias, float* __restrict__ out, int N) {
    int t = blockIdx.x * 256 + threadIdx.x;
    int n = t >> 6;
    if (n >= N) return;
    const int lane = t & 63;
    const int g  = lane >> 4;    // edge group 0..3
    const int c2 = lane & 15;    // half2 channel pair
    const int eo = lane & 3;     // edge slot within 4-cluster
    const float adst_n = adst[n];
    float l = 0.0f, accx = 0.0f, accy = 0.0f;
    if (g == 0) {                // self loop
        float p = __expf(leaky(asrc[n] + adst_n));
        float2 hv = __half22float2(h2[(size_t)n * 16 + c2]);
        l = p; accx = p * hv.x; accy = p * hv.y;
    }
    const int off = offs[n];
    const int deg = cnt[n];
    const int q = (deg + 3) >> 2;            // quarter size
    int j = off + g * q;
    const int jend = min(j + q, off + deg);
    for (; j < jend; j += 4) {
        const int last = jend - 1;
        const int jo = j + eo;
        int s0 = col[min(jo, last)];         // own slot only
        float p0 = 0.0f;
        if (jo <= last) p0 = __expf(leaky(asrc[s0] + adst_n));
        int s1 = __shfl_xor(s0, 1);
        int s2 = __shfl_xor(s0, 2);
        int s3 = __shfl_xor(s0, 3);
        float p1 = __shfl_xor(p0, 1);
        float p2 = __shfl_xor(p0, 2);
        float p3 = __shfl_xor(p0, 3);
        float2 h0 = __half22float2(h2[(size_t)s0 * 16 + c2]);
        float2 h1 = __half22float2(h2[(size_t)s1 * 16 + c2]);
        float2 hv2 = __half22float2(h2[(size_t)s2 * 16 + c2]);
        float2 h3 = __half22float2(h2[(size_t)s3 * 16 + c2]);
        l += (p0 + p1) + (p2 + p3);
        accx += p0 * h0.x + p1 * h1.x + p2 * hv2.x + p3 * h3.x;
        accy += p0 * h0.y + p1 * h1.y + p2 * hv2.y + p3 * h3.y;
    }
    l    += __shfl_xor(l, 16);    l    += __shfl_xor(l, 32);
    accx += __shfl_xor(accx, 16); accx += __shfl_xor(accx, 32);
    accy += __shfl_xor(accy, 16); accy += __shfl_xor(accy, 32);
    if (g == 0) {
        float inv = 1.0f / l;
        float2 bb = ((const float2*)bias)[c2];
        float2 o;
        o.x = fmaxf(accx * inv + bb.x, 0.0f);
        o.y = fmaxf(accy * inv + bb.y, 0.0f);
        ((float2*)out)[(size_t)n * 16 + c2] = o;
    }
}

extern "C" void kernel_launch(void* const* d_in, const int* in_sizes, int n_in,
                              void* d_out, int out_size, void* d_ws, size_t ws_size,
                              hipStream_t stream) {
    const float* x        = (const float*)d_in[0];
    const int*   eidx     = (const int*)d_in[1];   // [2, E] flat int32
    const float* W        = (const float*)d_in[2];
    const float* att_src  = (const float*)d_in[3];
    const float* att_dst  = (const float*)d_in[4];
    const float* bias     = (const float*)d_in[5];
    float* out = (float*)d_out;

    const int N = in_sizes[0] / IN_F;
    const int E = in_sizes[1] / 2;
    const int* src = eidx;
    const int* dst = eidx + E;

    const int NB  = (N + BK - 1) >> BK_SHIFT;    // 782 buckets
    const int epb = (E + NBLKA - 1) / NBLKA;     // edges per hist/bpart block

    // Workspace (4 B elems, ~21.9 MB)
    int* u = (int*)d_ws;
    size_t o = 0;
    __half2* h2   = (__half2*)(u + o); o += (size_t)N * 16;   // N*16 half2
    float*   asrc = (float*)(u + o);   o += N;
    float*   adst = (float*)(u + o);   o += N;
    int*     cnt  = u + o;             o += N;
    int*     offs = u + o;             o += N;
    int*     hist = u + o;             o += (size_t)NBLKA * NB;  // [blk][b]
    int*     bsum = u + o;             o += NBMAX;
    int*     col  = u + o;             o += E;
    int*     recs = u + o;             o += E;

    const int PB = (N + 63) / 64;                // MFMA proj blocks (64 nodes/block)
    const int scanBlocks = (NB + SB - 1) / SB;   // 13
    const int gatherBlocks = ((size_t)N * 64 + 255) / 256;

    k_projhist<<<PB + NBLKA, 256, 0, stream>>>(x, W, att_src, att_dst, h2, asrc, adst,
                                               dst, hist, N, NB, E, epb, PB);
    k_scan1<<<scanBlocks, 256, 0, stream>>>(hist, bsum, NB);
    k_bpart<<<NBLKA, 512, 0, stream>>>(src, dst, hist, bsum, recs, NB, E, epb);
    k_place<<<NB, 256, 0, stream>>>(recs, bsum, cnt, offs, col, NB, E, N);
    k_gather<<<gatherBlocks, 256, 0, stream>>>(col, offs, cnt, asrc, adst, h2, bias, out, N);
}

// Round 15
// 173.207 us; speedup vs baseline: 1.1239x; 1.1239x over previous
//
#include <hip/hip_runtime.h>
#include <hip/hip_fp16.h>
#include <math.h>

#define IN_F 64
#define OUT_F 32
#define NEG_SLOPE 0.2f

#define BK_SHIFT 7
#define BK 128           // nodes per bucket
#define NBMAX 1024       // max buckets (N <= 131072)
#define NBLKA 256        // edge-pass block count
#define LCAP 4096        // LDS col capacity per bucket (mean 2046, +45 sigma)
#define PSTAGE 16        // register staging depth (16*256 = LCAP)

typedef _Float16 half8_t __attribute__((ext_vector_type(8)));
typedef float float4_t __attribute__((ext_vector_type(4)));

__device__ __forceinline__ float leaky(float v) {
    return (v > 0.0f) ? v : NEG_SLOPE * v;
}

// Inclusive block scan, 256 threads. wsum: >=4-int LDS scratch.
__device__ __forceinline__ int incScan256(int v, int tid, int* wsum) {
    const int lane = tid & 63, wid = tid >> 6;
    #pragma unroll
    for (int m = 1; m < 64; m <<= 1) {
        int u = __shfl_up(v, m);
        if (lane >= m) v += u;
    }
    if (lane == 63) wsum[wid] = v;
    __syncthreads();
    int add = 0;
    for (int k = 0; k < wid; ++k) add += wsum[k];
    __syncthreads();
    return v + add;
}

// Inclusive block scan, 512 threads. wsum: >=8-int LDS scratch.
__device__ __forceinline__ int incScan512(int v, int tid, int* wsum) {
    const int lane = tid & 63, wid = tid >> 6;
    #pragma unroll
    for (int m = 1; m < 64; m <<= 1) {
        int u = __shfl_up(v, m);
        if (lane >= m) v += u;
    }
    if (lane == 63) wsum[wid] = v;
    __syncthreads();
    int add = 0;
    for (int k = 0; k < wid; ++k) add += wsum[k];
    __syncthreads();
    return v + add;
}

// Fused: blocks [0, PB) MFMA projection (16 nodes/wave, 64/block, no LDS);
// blocks [PB, PB+NBLKA) coarse histogram. hist layout: [b][blk] (r13-proven).
__global__ __launch_bounds__(256) void k_projhist(
        const float* __restrict__ x, const float* __restrict__ W,
        const float* __restrict__ att_src, const float* __restrict__ att_dst,
        __half2* __restrict__ h2, float* __restrict__ asrc, float* __restrict__ adst,
        const int* __restrict__ dst, int* __restrict__ hist,
        int N, int NB, int E, int epb, int PB) {
    __shared__ int smem[2560];               // 10 KB (hist role only)
    const int tid = threadIdx.x;

    if (blockIdx.x >= PB) {
        int* lh = smem;
        const int blk = blockIdx.x - PB;
        for (int i = tid; i < NB; i += 256) lh[i] = 0;
        __syncthreads();
        const int e0 = blk * epb, e1 = min(E, e0 + epb);
        for (int e = e0 + tid; e < e1; e += 256) atomicAdd(&lh[dst[e] >> BK_SHIFT], 1);
        __syncthreads();
        for (int b = tid; b < NB; b += 256) hist[(size_t)b * NBLKA + blk] = lh[b];
        return;
    }

    // ---- MFMA projection role (layouts HW-verified: §3 / m89) ----
    const int wv   = tid >> 6;
    const int lane = tid & 63;
    const int m    = lane & 15;
    const int quad = lane >> 4;
    const int node0 = (blockIdx.x * 4 + wv) * 16;
    if (node0 >= N) return;

    const int kb = quad * 8;
    half8_t b00, b01, b10, b11;
    #pragma unroll
    for (int j = 0; j < 8; ++j) {
        b00[j] = (_Float16)W[(kb + j) * OUT_F + m];
        b01[j] = (_Float16)W[(32 + kb + j) * OUT_F + m];
        b10[j] = (_Float16)W[(kb + j) * OUT_F + 16 + m];
        b11[j] = (_Float16)W[(32 + kb + j) * OUT_F + 16 + m];
    }
    const int row = min(node0 + m, N - 1);
    const float* xr = x + (size_t)row * IN_F + kb;
    float4_t xa = *(const float4_t*)(xr);
    float4_t xb = *(const float4_t*)(xr + 4);
    float4_t xc = *(const float4_t*)(xr + 32);
    float4_t xd = *(const float4_t*)(xr + 36);
    half8_t a0, a1;
    #pragma unroll
    for (int j = 0; j < 4; ++j) {
        a0[j] = (_Float16)xa[j]; a0[4 + j] = (_Float16)xb[j];
        a1[j] = (_Float16)xc[j]; a1[4 + j] = (_Float16)xd[j];
    }
    float4_t acc0 = {0.f, 0.f, 0.f, 0.f};
    float4_t acc1 = {0.f, 0.f, 0.f, 0.f};
    acc0 = __builtin_amdgcn_mfma_f32_16x16x32_f16(a0, b00, acc0, 0, 0, 0);
    acc0 = __builtin_amdgcn_mfma_f32_16x16x32_f16(a1, b01, acc0, 0, 0, 0);
    acc1 = __builtin_amdgcn_mfma_f32_16x16x32_f16(a0, b10, acc1, 0, 0, 0);
    acc1 = __builtin_amdgcn_mfma_f32_16x16x32_f16(a1, b11, acc1, 0, 0, 0);

    const float aS0 = att_src[m], aS1 = att_src[16 + m];
    const float aD0 = att_dst[m], aD1 = att_dst[16 + m];
    #pragma unroll
    for (int r = 0; r < 4; ++r) {
        const int node = node0 + quad * 4 + r;
        float h0 = acc0[r], h1 = acc1[r];
        float h0p = __shfl_xor(h0, 1);
        float h1p = __shfl_xor(h1, 1);
        if (node < N && (m & 1) == 0) {
            __half2 hv;
            hv.x = __float2half_rn(h0); hv.y = __float2half_rn(h0p);
            h2[(size_t)node * 16 + (m >> 1)] = hv;
            __half2 hw;
            hw.x = __float2half_rn(h1); hw.y = __float2half_rn(h1p);
            h2[(size_t)node * 16 + 8 + (m >> 1)] = hw;
        }
        float vs = h0 * aS0 + h1 * aS1;
        float vd = h0 * aD0 + h1 * aD1;
        #pragma unroll
        for (int mm = 1; mm < 16; mm <<= 1) {
            vs += __shfl_xor(vs, mm);
            vd += __shfl_xor(vd, mm);
        }
        if (node < N && m == 0) {
            asrc[node] = vs;
            adst[node] = vd;
        }
    }
}

// Scan 1: one block per bucket; exclusive scan of hist[b][0..NBLKA) in place,
// bucket total -> bsum[b].  (r13-proven)
__global__ __launch_bounds__(256) void k_scan1(int* __restrict__ hist,
                                               int* __restrict__ bsum, int NB) {
    __shared__ int wsum[4];
    const int b = blockIdx.x, tid = threadIdx.x;
    int v = hist[(size_t)b * NBLKA + tid];
    const int inc = incScan256(v, tid, wsum);
    hist[(size_t)b * NBLKA + tid] = inc - v;
    if (tid == 255) bsum[b] = inc;
}

// Pass B: 512 threads/block. Locally scan bucket totals -> bbase (LDS), seed
// per-bucket cursors, place packed records (d&127)<<17 | s.  (r13-proven)
__global__ __launch_bounds__(512) void k_bpart(const int* __restrict__ src,
                                               const int* __restrict__ dst,
                                               const int* __restrict__ hist,
                                               const int* __restrict__ bsum,
                                               int* __restrict__ recs,
                                               int NB, int E, int epb) {
    __shared__ int tt[NBMAX];
    __shared__ int lcur[NBMAX];
    __shared__ int wsum[8];
    const int tid = threadIdx.x, blk = blockIdx.x;
    for (int i = tid; i < NBMAX; i += 512) tt[i] = (i < NB) ? bsum[i] : 0;
    __syncthreads();
    {
        int a0 = tt[tid * 2], a1 = tt[tid * 2 + 1];
        int s = a0 + a1;
        int inc = incScan512(s, tid, wsum);
        int run = inc - s;
        tt[tid * 2] = run; run += a0;
        tt[tid * 2 + 1] = run;
    }
    __syncthreads();
    for (int b = tid; b < NB; b += 512)
        lcur[b] = hist[(size_t)b * NBLKA + blk] + tt[b];
    __syncthreads();
    const int e0 = blk * epb, e1 = min(E, e0 + epb);
    for (int e = e0 + tid; e < e1; e += 512) {
        int s = src[e];
        int d = dst[e];
        int p = atomicAdd(&lcur[d >> BK_SHIFT], 1);   // LDS cursor, block-private
        recs[p] = ((d & (BK - 1)) << 17) | s;
    }
}

// Fused place+gather: one block per 128-node bucket. Reads its recs segment
// once, builds the fine CSR in LDS (register-staged count + scan + place into
// lcol), then runs the r13 per-node wave gather with col served from LDS.
// Main-path gather code is r13's proven version (redundant per-lane exp:
// keeps loads independent — r14 showed shfl-dedup couples the chain).
__global__ __launch_bounds__(256) void k_bgather(
        const int* __restrict__ recs, const int* __restrict__ bsum,
        const float* __restrict__ asrc, const float* __restrict__ adst,
        const __half2* __restrict__ h2, const float* __restrict__ bias,
        float* __restrict__ out, int NB, int E, int N) {
    __shared__ int sh[5512];
    int* tt      = sh;             // 1024 (dead after cb0/cb1)
    int* lcol    = sh + 1024;      // LCAP = 4096
    int* fineCnt = sh + 5120;      // 128
    int* off2    = sh + 5248;      // 128
    int* cur     = sh + 5376;      // 128
    int* wsum    = sh + 5504;      // 8
    const int b = blockIdx.x, tid = threadIdx.x;
    const int nb0 = b << BK_SHIFT;

    // ---- bucket bounds via local scan of bsum ----
    for (int i = tid; i < NBMAX; i += 256) tt[i] = (i < NB) ? bsum[i] : 0;
    __syncthreads();
    {
        int a0 = tt[tid * 4], a1 = tt[tid * 4 + 1], a2 = tt[tid * 4 + 2], a3 = tt[tid * 4 + 3];
        int s = a0 + a1 + a2 + a3;
        int inc = incScan256(s, tid, wsum);
        int run = inc - s;
        tt[tid * 4] = run;     run += a0;
        tt[tid * 4 + 1] = run; run += a1;
        tt[tid * 4 + 2] = run; run += a2;
        tt[tid * 4 + 3] = run;
    }
    __syncthreads();
    const int cb0 = tt[b];
    const int cb1 = (b + 1 < NB) ? tt[b + 1] : E;
    const int count = cb1 - cb0;
    __syncthreads();               // tt dead below

    if (count > LCAP) {
        // ---- fallback (statistically never): LDS-accumulate, r10-style ----
        float* s_acc  = (float*)sh;            // 128*33 floats
        float* s_adst = (float*)(sh + 4224);   // 128
        for (int i = tid; i < BK * 33; i += 256) s_acc[i] = 0.0f;
        for (int i = tid; i < BK; i += 256) {
            int n = nb0 + i;
            s_adst[i] = (n < N) ? adst[n] : 0.0f;
        }
        __syncthreads();
        const int slot = tid >> 4, c2 = tid & 15;
        for (int i0 = 0; i0 < count; i0 += 16) {
            int i = i0 + slot;
            if (i < count) {
                int r  = recs[cb0 + i];
                int s  = r & 0x1FFFF;
                int dl = r >> 17;
                float p = __expf(leaky(asrc[s] + s_adst[dl]));
                float2 hv = __half22float2(h2[(size_t)s * 16 + c2]);
                atomicAdd(&s_acc[dl * 33 + 2 * c2],     p * hv.x);
                atomicAdd(&s_acc[dl * 33 + 2 * c2 + 1], p * hv.y);
                if (c2 == 0) atomicAdd(&s_acc[dl * 33 + 32], p);
            }
        }
        __syncthreads();
        const int c = tid & 31;
        const float bc = bias[c];
        for (int nl = tid >> 5; nl < BK; nl += 8) {
            int n = nb0 + nl;
            if (n >= N) break;
            float pself = __expf(leaky(asrc[n] + s_adst[nl]));
            float hc = __half2float(((const __half*)h2)[(size_t)n * 32 + c]);
            float l = s_acc[nl * 33 + 32] + pself;
            float v = (s_acc[nl * 33 + c] + pself * hc) / l + bc;
            out[(size_t)n * 32 + c] = fmaxf(v, 0.0f);
        }
        return;
    }

    // ---- fine CSR in LDS (place logic, register-staged) ----
    int myrec[PSTAGE];
    if (tid < BK) fineCnt[tid] = 0;
    __syncthreads();
    #pragma unroll
    for (int k = 0; k < PSTAGE; ++k) {
        int i = tid + k * 256;
        if (i < count) {
            int v = recs[cb0 + i];
            myrec[k] = v;
            atomicAdd(&fineCnt[v >> 17], 1);
        }
    }
    __syncthreads();
    {
        const int v0 = (tid < BK) ? fineCnt[tid] : 0;
        const int inc = incScan256(v0, tid, wsum);
        if (tid < BK) {
            off2[tid] = inc - v0;
            cur[tid]  = inc - v0;
        }
    }
    __syncthreads();
    #pragma unroll
    for (int k = 0; k < PSTAGE; ++k) {
        int i = tid + k * 256;
        if (i < count) {
            int r = myrec[k];
            int p = atomicAdd(&cur[r >> 17], 1);
            lcol[p] = r & 0x1FFFF;
        }
    }
    __syncthreads();

    // ---- per-node wave gather (r13-proven body; col from LDS) ----
    const int lane = tid & 63;
    const int g  = lane >> 4;    // edge group 0..3
    const int c2 = lane & 15;    // half2 channel pair
    for (int nl = tid >> 6; nl < BK; nl += 4) {   // 4 waves, 32 nodes each
        const int n = nb0 + nl;
        if (n >= N) break;
        const float adst_n = adst[n];
        float l = 0.0f, accx = 0.0f, accy = 0.0f;
        if (g == 0) {            // self loop
            float p = __expf(leaky(asrc[n] + adst_n));
            float2 hv = __half22float2(h2[(size_t)n * 16 + c2]);
            l = p; accx = p * hv.x; accy = p * hv.y;
        }
        const int off = off2[nl];
        const int deg = fineCnt[nl];
        const int q = (deg + 3) >> 2;
        int j = off + g * q;
        const int jend = min(j + q, off + deg);
        for (; j < jend; j += 4) {
            const int last = jend - 1;
            int i1 = min(j + 1, last), i2 = min(j + 2, last), i3 = min(j + 3, last);
            int s0 = lcol[j], s1 = lcol[i1], s2 = lcol[i2], s3 = lcol[i3];
            float a0 = asrc[s0], a1 = asrc[s1], a2 = asrc[s2], a3 = asrc[s3];
            float2 h0 = __half22float2(h2[(size_t)s0 * 16 + c2]);
            float2 h1 = __half22float2(h2[(size_t)s1 * 16 + c2]);
            float2 hv2 = __half22float2(h2[(size_t)s2 * 16 + c2]);
            float2 h3 = __half22float2(h2[(size_t)s3 * 16 + c2]);
            float p0 = __expf(leaky(a0 + adst_n));
            float p1 = (j + 1 < jend) ? __expf(leaky(a1 + adst_n)) : 0.0f;
            float p2 = (j + 2 < jend) ? __expf(leaky(a2 + adst_n)) : 0.0f;
            float p3 = (j + 3 < jend) ? __expf(leaky(a3 + adst_n)) : 0.0f;
            l += (p0 + p1) + (p2 + p3);
            accx += p0 * h0.x + p1 * h1.x + p2 * hv2.x + p3 * h3.x;
            accy += p0 * h0.y + p1 * h1.y + p2 * hv2.y + p3 * h3.y;
        }
        l    += __shfl_xor(l, 16);    l    += __shfl_xor(l, 32);
        accx += __shfl_xor(accx, 16); accx += __shfl_xor(accx, 32);
        accy += __shfl_xor(accy, 16); accy += __shfl_xor(accy, 32);
        if (g == 0) {
            float inv = 1.0f / l;
            float2 bb = ((const float2*)bias)[c2];
            float2 o;
            o.x = fmaxf(accx * inv + bb.x, 0.0f);
            o.y = fmaxf(accy * inv + bb.y, 0.0f);
            ((float2*)out)[(size_t)n * 16 + c2] = o;
        }
    }
}

extern "C" void kernel_launch(void* const* d_in, const int* in_sizes, int n_in,
                              void* d_out, int out_size, void* d_ws, size_t ws_size,
                              hipStream_t stream) {
    const float* x        = (const float*)d_in[0];
    const int*   eidx     = (const int*)d_in[1];   // [2, E] flat int32
    const float* W        = (const float*)d_in[2];
    const float* att_src  = (const float*)d_in[3];
    const float* att_dst  = (const float*)d_in[4];
    const float* bias     = (const float*)d_in[5];
    float* out = (float*)d_out;

    const int N = in_sizes[0] / IN_F;
    const int E = in_sizes[1] / 2;
    const int* src = eidx;
    const int* dst = eidx + E;

    const int NB  = (N + BK - 1) >> BK_SHIFT;    // 782 buckets
    const int epb = (E + NBLKA - 1) / NBLKA;     // edges per hist/bpart block

    // Workspace (4 B elems, ~15.5 MB)
    int* u = (int*)d_ws;
    size_t o = 0;
    __half2* h2   = (__half2*)(u + o); o += (size_t)N * 16;   // N*16 half2
    float*   asrc = (float*)(u + o);   o += N;
    float*   adst = (float*)(u + o);   o += N;
    int*     hist = u + o;             o += (size_t)NB * NBLKA;  // [b][blk]
    int*     bsum = u + o;             o += NBMAX;
    int*     recs = u + o;             o += E;

    const int PB = (N + 63) / 64;                // MFMA proj blocks (64 nodes/block)

    k_projhist<<<PB + NBLKA, 256, 0, stream>>>(x, W, att_src, att_dst, h2, asrc, adst,
                                               dst, hist, N, NB, E, epb, PB);
    k_scan1<<<NB, 256, 0, stream>>>(hist, bsum, NB);
    k_bpart<<<NBLKA, 512, 0, stream>>>(src, dst, hist, bsum, recs, NB, E, epb);
    k_bgather<<<NB, 256, 0, stream>>>(recs, bsum, asrc, adst, h2, bias, out, NB, E, N);
}

// Round 16
// 173.171 us; speedup vs baseline: 1.1242x; 1.0002x over previous
//
#include <hip/hip_runtime.h>
#include <hip/hip_fp16.h>
#include <math.h>

#define IN_F 64
#define OUT_F 32
#define NEG_SLOPE 0.2f

#define BK_SHIFT 7
#define BK 128           // nodes per bucket
#define NBMAX 1024       // max buckets (N <= 131072)
#define NBLKA 256        // edge-pass block count
#define PSTAGE 10        // k_place register staging (mean count ~2046 < 2560)

typedef _Float16 half8_t __attribute__((ext_vector_type(8)));
typedef float float4_t __attribute__((ext_vector_type(4)));

__device__ __forceinline__ float leaky(float v) {
    return (v > 0.0f) ? v : NEG_SLOPE * v;
}

// Inclusive block scan, 256 threads. wsum: >=4-int LDS scratch.
__device__ __forceinline__ int incScan256(int v, int tid, int* wsum) {
    const int lane = tid & 63, wid = tid >> 6;
    #pragma unroll
    for (int m = 1; m < 64; m <<= 1) {
        int u = __shfl_up(v, m);
        if (lane >= m) v += u;
    }
    if (lane == 63) wsum[wid] = v;
    __syncthreads();
    int add = 0;
    for (int k = 0; k < wid; ++k) add += wsum[k];
    __syncthreads();
    return v + add;
}

// Inclusive block scan, 512 threads. wsum: >=8-int LDS scratch.
__device__ __forceinline__ int incScan512(int v, int tid, int* wsum) {
    const int lane = tid & 63, wid = tid >> 6;
    #pragma unroll
    for (int m = 1; m < 64; m <<= 1) {
        int u = __shfl_up(v, m);
        if (lane >= m) v += u;
    }
    if (lane == 63) wsum[wid] = v;
    __syncthreads();
    int add = 0;
    for (int k = 0; k < wid; ++k) add += wsum[k];
    __syncthreads();
    return v + add;
}

// Fused: blocks [0, PB) MFMA projection (16 nodes/wave, 64/block, no LDS);
// blocks [PB, PB+NBLKA) coarse histogram. hist layout: [b][blk]. (r13-proven)
__global__ __launch_bounds__(256) void k_projhist(
        const float* __restrict__ x, const float* __restrict__ W,
        const float* __restrict__ att_src, const float* __restrict__ att_dst,
        __half2* __restrict__ h2, float* __restrict__ asrc, float* __restrict__ adst,
        const int* __restrict__ dst, int* __restrict__ hist,
        int N, int NB, int E, int epb, int PB) {
    __shared__ int smem[2560];               // 10 KB (hist role only)
    const int tid = threadIdx.x;

    if (blockIdx.x >= PB) {
        int* lh = smem;
        const int blk = blockIdx.x - PB;
        for (int i = tid; i < NB; i += 256) lh[i] = 0;
        __syncthreads();
        const int e0 = blk * epb, e1 = min(E, e0 + epb);
        for (int e = e0 + tid; e < e1; e += 256) atomicAdd(&lh[dst[e] >> BK_SHIFT], 1);
        __syncthreads();
        for (int b = tid; b < NB; b += 256) hist[(size_t)b * NBLKA + blk] = lh[b];
        return;
    }

    // ---- MFMA projection role (layouts HW-verified: §3 / m89) ----
    const int wv   = tid >> 6;
    const int lane = tid & 63;
    const int m    = lane & 15;
    const int quad = lane >> 4;
    const int node0 = (blockIdx.x * 4 + wv) * 16;
    if (node0 >= N) return;

    const int kb = quad * 8;
    half8_t b00, b01, b10, b11;
    #pragma unroll
    for (int j = 0; j < 8; ++j) {
        b00[j] = (_Float16)W[(kb + j) * OUT_F + m];
        b01[j] = (_Float16)W[(32 + kb + j) * OUT_F + m];
        b10[j] = (_Float16)W[(kb + j) * OUT_F + 16 + m];
        b11[j] = (_Float16)W[(32 + kb + j) * OUT_F + 16 + m];
    }
    const int row = min(node0 + m, N - 1);
    const float* xr = x + (size_t)row * IN_F + kb;
    float4_t xa = *(const float4_t*)(xr);
    float4_t xb = *(const float4_t*)(xr + 4);
    float4_t xc = *(const float4_t*)(xr + 32);
    float4_t xd = *(const float4_t*)(xr + 36);
    half8_t a0, a1;
    #pragma unroll
    for (int j = 0; j < 4; ++j) {
        a0[j] = (_Float16)xa[j]; a0[4 + j] = (_Float16)xb[j];
        a1[j] = (_Float16)xc[j]; a1[4 + j] = (_Float16)xd[j];
    }
    float4_t acc0 = {0.f, 0.f, 0.f, 0.f};
    float4_t acc1 = {0.f, 0.f, 0.f, 0.f};
    acc0 = __builtin_amdgcn_mfma_f32_16x16x32_f16(a0, b00, acc0, 0, 0, 0);
    acc0 = __builtin_amdgcn_mfma_f32_16x16x32_f16(a1, b01, acc0, 0, 0, 0);
    acc1 = __builtin_amdgcn_mfma_f32_16x16x32_f16(a0, b10, acc1, 0, 0, 0);
    acc1 = __builtin_amdgcn_mfma_f32_16x16x32_f16(a1, b11, acc1, 0, 0, 0);

    const float aS0 = att_src[m], aS1 = att_src[16 + m];
    const float aD0 = att_dst[m], aD1 = att_dst[16 + m];
    #pragma unroll
    for (int r = 0; r < 4; ++r) {
        const int node = node0 + quad * 4 + r;
        float h0 = acc0[r], h1 = acc1[r];
        float h0p = __shfl_xor(h0, 1);
        float h1p = __shfl_xor(h1, 1);
        if (node < N && (m & 1) == 0) {
            __half2 hv;
            hv.x = __float2half_rn(h0); hv.y = __float2half_rn(h0p);
            h2[(size_t)node * 16 + (m >> 1)] = hv;
            __half2 hw;
            hw.x = __float2half_rn(h1); hw.y = __float2half_rn(h1p);
            h2[(size_t)node * 16 + 8 + (m >> 1)] = hw;
        }
        float vs = h0 * aS0 + h1 * aS1;
        float vd = h0 * aD0 + h1 * aD1;
        #pragma unroll
        for (int mm = 1; mm < 16; mm <<= 1) {
            vs += __shfl_xor(vs, mm);
            vd += __shfl_xor(vd, mm);
        }
        if (node < N && m == 0) {
            asrc[node] = vs;
            adst[node] = vd;
        }
    }
}

// Scan 1: one block per bucket; exclusive scan of hist[b][0..NBLKA) in place,
// bucket total -> bsum[b].  (r13-proven)
__global__ __launch_bounds__(256) void k_scan1(int* __restrict__ hist,
                                               int* __restrict__ bsum, int NB) {
    __shared__ int wsum[4];
    const int b = blockIdx.x, tid = threadIdx.x;
    int v = hist[(size_t)b * NBLKA + tid];
    const int inc = incScan256(v, tid, wsum);
    hist[(size_t)b * NBLKA + tid] = inc - v;
    if (tid == 255) bsum[b] = inc;
}

// Pass B: 512 threads/block. Locally scan bucket totals -> bbase (LDS), seed
// per-bucket cursors, place packed records (d&127)<<17 | s.  (r13-proven)
__global__ __launch_bounds__(512) void k_bpart(const int* __restrict__ src,
                                               const int* __restrict__ dst,
                                               const int* __restrict__ hist,
                                               const int* __restrict__ bsum,
                                               int* __restrict__ recs,
                                               int NB, int E, int epb) {
    __shared__ int tt[NBMAX];
    __shared__ int lcur[NBMAX];
    __shared__ int wsum[8];
    const int tid = threadIdx.x, blk = blockIdx.x;
    for (int i = tid; i < NBMAX; i += 512) tt[i] = (i < NB) ? bsum[i] : 0;
    __syncthreads();
    {
        int a0 = tt[tid * 2], a1 = tt[tid * 2 + 1];
        int s = a0 + a1;
        int inc = incScan512(s, tid, wsum);
        int run = inc - s;
        tt[tid * 2] = run; run += a0;
        tt[tid * 2 + 1] = run;
    }
    __syncthreads();
    for (int b = tid; b < NB; b += 512)
        lcur[b] = hist[(size_t)b * NBLKA + blk] + tt[b];
    __syncthreads();
    const int e0 = blk * epb, e1 = min(E, e0 + epb);
    for (int e = e0 + tid; e < e1; e += 512) {
        int s = src[e];
        int d = dst[e];
        int p = atomicAdd(&lcur[d >> BK_SHIFT], 1);   // LDS cursor, block-private
        recs[p] = ((d & (BK - 1)) << 17) | s;
    }
}

// Pass C: one block per bucket (128 nodes). Local bbase scan for cb0/cb1,
// register-staged records, fine histogram + scan, emit cnt/offs, place col.
// (r13-proven)
__global__ __launch_bounds__(256) void k_place(const int* __restrict__ recs,
                                               const int* __restrict__ bsum,
                                               int* __restrict__ cnt,
                                               int* __restrict__ offs,
                                               int* __restrict__ col,
                                               int NB, int E, int N) {
    __shared__ int tt[NBMAX];
    __shared__ int fineCnt[BK];
    __shared__ int cur[BK];
    __shared__ int wsum[4];
    const int b = blockIdx.x, tid = threadIdx.x;
    for (int i = tid; i < NBMAX; i += 256) tt[i] = (i < NB) ? bsum[i] : 0;
    __syncthreads();
    {
        int a0 = tt[tid * 4], a1 = tt[tid * 4 + 1], a2 = tt[tid * 4 + 2], a3 = tt[tid * 4 + 3];
        int s = a0 + a1 + a2 + a3;
        int inc = incScan256(s, tid, wsum);
        int run = inc - s;
        tt[tid * 4] = run;     run += a0;
        tt[tid * 4 + 1] = run; run += a1;
        tt[tid * 4 + 2] = run; run += a2;
        tt[tid * 4 + 3] = run;
    }
    __syncthreads();
    const int cb0 = tt[b];
    const int cb1 = (b + 1 < NB) ? tt[b + 1] : E;
    const int count = cb1 - cb0;
    int myrec[PSTAGE];
    if (tid < BK) fineCnt[tid] = 0;
    __syncthreads();
    #pragma unroll
    for (int k = 0; k < PSTAGE; ++k) {
        int i = tid + k * 256;
        if (i < count) {
            int v = recs[cb0 + i];
            myrec[k] = v;
            atomicAdd(&fineCnt[v >> 17], 1);
        }
    }
    for (int i = tid + PSTAGE * 256; i < count; i += 256)   // statistically never
        atomicAdd(&fineCnt[recs[cb0 + i] >> 17], 1);
    __syncthreads();
    const int v0 = (tid < BK) ? fineCnt[tid] : 0;
    const int inc = incScan256(v0, tid, wsum);
    const int excl = inc - v0;
    if (tid < BK) {
        const int node = (b << BK_SHIFT) + tid;
        if (node < N) {
            cnt[node]  = v0;
            offs[node] = cb0 + excl;
        }
        cur[tid] = cb0 + excl;
    }
    __syncthreads();
    #pragma unroll
    for (int k = 0; k < PSTAGE; ++k) {
        int i = tid + k * 256;
        if (i < count) {
            int r = myrec[k];
            int p = atomicAdd(&cur[r >> 17], 1);
            col[p] = r & 0x1FFFF;
        }
    }
    for (int i = tid + PSTAGE * 256; i < count; i += 256) {
        int r = recs[cb0 + i];
        int p = atomicAdd(&cur[r >> 17], 1);
        col[p] = r & 0x1FFFF;
    }
}

// Gather: one wave per node, 8 groups x 8 lanes; each lane covers 4 channels
// via one 8 B h2 load (two half2s). Chunks of 2 edges, predicated. Lanes stay
// fully independent (r14 lesson: no cross-lane sharing in the load chain);
// redundant col/asrc/exp issue is 8x instead of 16x. Merge via shfl_xor(8/16/32);
// group 0 writes a float4 (128 B coalesced row).
__global__ void k_gather(const int* __restrict__ col, const int* __restrict__ offs,
                         const int* __restrict__ cnt, const float* __restrict__ asrc,
                         const float* __restrict__ adst, const __half2* __restrict__ h2,
                         const float* __restrict__ bias, float* __restrict__ out, int N) {
    int t = blockIdx.x * 256 + threadIdx.x;
    int n = t >> 6;
    if (n >= N) return;
    const int lane = t & 63;
    const int g  = lane >> 3;    // edge group 0..7
    const int c4 = lane & 7;     // channel quad (channels 4*c4 .. 4*c4+3)
    const float adst_n = adst[n];
    float l = 0.0f, ax0 = 0.0f, ay0 = 0.0f, ax1 = 0.0f, ay1 = 0.0f;
    if (g == 0) {                // self loop
        float p = __expf(leaky(asrc[n] + adst_n));
        float2 raw = ((const float2*)(h2 + (size_t)n * 16))[c4];
        float2 f01 = __half22float2(*(const __half2*)&raw.x);
        float2 f23 = __half22float2(*(const __half2*)&raw.y);
        l = p;
        ax0 = p * f01.x; ay0 = p * f01.y;
        ax1 = p * f23.x; ay1 = p * f23.y;
    }
    const int off = offs[n];
    const int deg = cnt[n];
    const int q = (deg + 7) >> 3;            // eighth size
    int j = off + g * q;
    const int jend = min(j + q, off + deg);
    for (; j < jend; j += 2) {
        const int last = jend - 1;
        const int i1 = min(j + 1, last);
        int s0 = col[j], s1 = col[i1];
        float a0 = asrc[s0], a1 = asrc[s1];
        float2 r0 = ((const float2*)(h2 + (size_t)s0 * 16))[c4];
        float2 r1 = ((const float2*)(h2 + (size_t)s1 * 16))[c4];
        float p0 = __expf(leaky(a0 + adst_n));
        float p1 = (j + 1 < jend) ? __expf(leaky(a1 + adst_n)) : 0.0f;
        float2 f0a = __half22float2(*(const __half2*)&r0.x);
        float2 f0b = __half22float2(*(const __half2*)&r0.y);
        float2 f1a = __half22float2(*(const __half2*)&r1.x);
        float2 f1b = __half22float2(*(const __half2*)&r1.y);
        l   += p0 + p1;
        ax0 += p0 * f0a.x + p1 * f1a.x;
        ay0 += p0 * f0a.y + p1 * f1a.y;
        ax1 += p0 * f0b.x + p1 * f1b.x;
        ay1 += p0 * f0b.y + p1 * f1b.y;
    }
    l   += __shfl_xor(l, 8);   l   += __shfl_xor(l, 16);   l   += __shfl_xor(l, 32);
    ax0 += __shfl_xor(ax0, 8); ax0 += __shfl_xor(ax0, 16); ax0 += __shfl_xor(ax0, 32);
    ay0 += __shfl_xor(ay0, 8); ay0 += __shfl_xor(ay0, 16); ay0 += __shfl_xor(ay0, 32);
    ax1 += __shfl_xor(ax1, 8); ax1 += __shfl_xor(ax1, 16); ax1 += __shfl_xor(ax1, 32);
    ay1 += __shfl_xor(ay1, 8); ay1 += __shfl_xor(ay1, 16); ay1 += __shfl_xor(ay1, 32);
    if (g == 0) {
        float inv = 1.0f / l;
        float4 bb = ((const float4*)bias)[c4];
        float4 o;
        o.x = fmaxf(ax0 * inv + bb.x, 0.0f);
        o.y = fmaxf(ay0 * inv + bb.y, 0.0f);
        o.z = fmaxf(ax1 * inv + bb.z, 0.0f);
        o.w = fmaxf(ay1 * inv + bb.w, 0.0f);
        ((float4*)out)[(size_t)n * 8 + c4] = o;
    }
}

extern "C" void kernel_launch(void* const* d_in, const int* in_sizes, int n_in,
                              void* d_out, int out_size, void* d_ws, size_t ws_size,
                              hipStream_t stream) {
    const float* x        = (const float*)d_in[0];
    const int*   eidx     = (const int*)d_in[1];   // [2, E] flat int32
    const float* W        = (const float*)d_in[2];
    const float* att_src  = (const float*)d_in[3];
    const float* att_dst  = (const float*)d_in[4];
    const float* bias     = (const float*)d_in[5];
    float* out = (float*)d_out;

    const int N = in_sizes[0] / IN_F;
    const int E = in_sizes[1] / 2;
    const int* src = eidx;
    const int* dst = eidx + E;

    const int NB  = (N + BK - 1) >> BK_SHIFT;    // 782 buckets
    const int epb = (E + NBLKA - 1) / NBLKA;     // edges per hist/bpart block

    // Workspace (4 B elems, ~21.9 MB)
    int* u = (int*)d_ws;
    size_t o = 0;
    __half2* h2   = (__half2*)(u + o); o += (size_t)N * 16;   // N*16 half2
    float*   asrc = (float*)(u + o);   o += N;
    float*   adst = (float*)(u + o);   o += N;
    int*     cnt  = u + o;             o += N;
    int*     offs = u + o;             o += N;
    int*     hist = u + o;             o += (size_t)NB * NBLKA;  // [b][blk]
    int*     bsum = u + o;             o += NBMAX;
    int*     col  = u + o;             o += E;
    int*     recs = u + o;             o += E;

    const int PB = (N + 63) / 64;                // MFMA proj blocks (64 nodes/block)
    const int gatherBlocks = ((size_t)N * 64 + 255) / 256;

    k_projhist<<<PB + NBLKA, 256, 0, stream>>>(x, W, att_src, att_dst, h2, asrc, adst,
                                               dst, hist, N, NB, E, epb, PB);
    k_scan1<<<NB, 256, 0, stream>>>(hist, bsum, NB);
    k_bpart<<<NBLKA, 512, 0, stream>>>(src, dst, hist, bsum, recs, NB, E, epb);
    k_place<<<NB, 256, 0, stream>>>(recs, bsum, cnt, offs, col, NB, E, N);
    k_gather<<<gatherBlocks, 256, 0, stream>>>(col, offs, cnt, asrc, adst, h2, bias, out, N);
}